// Round 4
// baseline (156.213 us; speedup 1.0000x reference)
//
#include <hip/hip_runtime.h>
#include <math.h>

#define NB 8192
#define ND 128
#define NJB (NB / 128)   // 64 column-block partials per row

typedef __bf16 bf16x8 __attribute__((ext_vector_type(8)));
typedef float f32x4 __attribute__((ext_vector_type(4)));

__device__ __forceinline__ unsigned short f2bf(float f) {
    union { float f; unsigned u; } v; v.f = f;
    unsigned r = v.u + 0x7FFFu + ((v.u >> 16) & 1u);  // RNE, inputs finite
    return (unsigned short)(r >> 16);
}

// prep: 16 lanes per row. seg 0: convert sk + ||sk||^2; seg 1: convert im +
// ||im||^2; seg 2: diag[i] = ||sk_i - im_i|| (fp32). Also zeroes gacc/ticket.
__global__ void prep_kernel(const float* __restrict__ sk, const float* __restrict__ im,
                            ushort4* __restrict__ skb4, ushort4* __restrict__ imb4,
                            float* __restrict__ skn, float* __restrict__ imn,
                            float* __restrict__ diag, float* __restrict__ gacc,
                            unsigned* __restrict__ ticket) {
    if (blockIdx.x == 0 && threadIdx.x == 0) { *gacc = 0.f; *ticket = 0u; }
    int gtid = blockIdx.x * 256 + threadIdx.x;
    int row = gtid >> 4;
    int l16 = gtid & 15;
    int seg = row >> 13;          // NB == 2^13
    int r = row & (NB - 1);
    size_t off = (size_t)r * ND + l16 * 8;
    float s;
    if (seg == 2) {
        const float4* a4 = reinterpret_cast<const float4*>(sk + off);
        const float4* b4 = reinterpret_cast<const float4*>(im + off);
        float4 a0 = a4[0], a1 = a4[1], b0 = b4[0], b1 = b4[1];
        float d0 = a0.x - b0.x, d1 = a0.y - b0.y, d2 = a0.z - b0.z, d3 = a0.w - b0.w;
        float d4 = a1.x - b1.x, d5 = a1.y - b1.y, d6 = a1.z - b1.z, d7 = a1.w - b1.w;
        s = d0*d0 + d1*d1 + d2*d2 + d3*d3 + d4*d4 + d5*d5 + d6*d6 + d7*d7;
    } else {
        const float* src = (seg ? im : sk) + off;
        float4 a = *reinterpret_cast<const float4*>(src);
        float4 b = *reinterpret_cast<const float4*>(src + 4);
        s = a.x*a.x + a.y*a.y + a.z*a.z + a.w*a.w
          + b.x*b.x + b.y*b.y + b.z*b.z + b.w*b.w;
        ushort4 pa, pb;
        pa.x = f2bf(a.x); pa.y = f2bf(a.y); pa.z = f2bf(a.z); pa.w = f2bf(a.w);
        pb.x = f2bf(b.x); pb.y = f2bf(b.y); pb.z = f2bf(b.z); pb.w = f2bf(b.w);
        ushort4* dst = (seg ? imb4 : skb4) + (off >> 2);
        dst[0] = pa; dst[1] = pb;
    }
    s += __shfl_xor(s, 1);
    s += __shfl_xor(s, 2);
    s += __shfl_xor(s, 4);
    s += __shfl_xor(s, 8);
    if (l16 == 0) {
        if (seg == 0)      skn[r] = s;
        else if (seg == 1) imn[r] = s;
        else               diag[r] = sqrtf(s);
    }
}

// tile: 128x128 per 512-thread block (8 waves); each wave 32(j) x 64(i) ->
// acc[2][4] (32 AGPR) + double-buffered fragments (48 VGPR) -> ~110 regs,
// 4 waves/SIMD. Swapped operands keep the j-sum lane-local. Norm loads hoisted.
__global__ void __launch_bounds__(512, 4) tile_kernel(
    const unsigned short* __restrict__ skb, const unsigned short* __restrict__ imb,
    const float* __restrict__ skn, const float* __restrict__ imn,
    float* __restrict__ partial) {
    __shared__ float lds_part[4][128];
    const int t = threadIdx.x;
    const int wid = t >> 6, lane = t & 63;
    const int wr = wid >> 1, wc = wid & 1;   // wr: j-quarter (32 rows), wc: i-half (64)
    const int hi = lane >> 4, lo = lane & 15;
    const int tI = blockIdx.x * 128;         // sk (i) base
    const int tJ = blockIdx.y * 128;         // im (j) base
    const int ibase = tI + wc * 64;
    const int jbase = tJ + wr * 32;

    // Hoist epilogue operands so their latency hides under the MFMA phase.
    float skv[4];
#pragma unroll
    for (int n = 0; n < 4; ++n) skv[n] = skn[ibase + n * 16 + lo];
    float imnv[2][4];
#pragma unroll
    for (int m = 0; m < 2; ++m) {
        float4 v = *reinterpret_cast<const float4*>(imn + jbase + m * 16 + hi * 4);
        imnv[m][0] = v.x; imnv[m][1] = v.y; imnv[m][2] = v.z; imnv[m][3] = v.w;
    }

    const unsigned short* Ab = imb + (size_t)(jbase + lo) * ND + hi * 8;
    const unsigned short* Bb = skb + (size_t)(ibase + lo) * ND + hi * 8;

    f32x4 acc[2][4];   // acc[m][n]: j = jbase+m*16+hi*4+r, i = ibase+n*16+lo
#pragma unroll
    for (int m = 0; m < 2; ++m)
#pragma unroll
        for (int n = 0; n < 4; ++n)
            acc[m][n] = (f32x4){0.f, 0.f, 0.f, 0.f};

    bf16x8 af[2][2], bfr[2][4];
#pragma unroll
    for (int m = 0; m < 2; ++m)
        af[0][m] = *reinterpret_cast<const bf16x8*>(Ab + (size_t)m * 16 * ND);
#pragma unroll
    for (int n = 0; n < 4; ++n)
        bfr[0][n] = *reinterpret_cast<const bf16x8*>(Bb + (size_t)n * 16 * ND);
#pragma unroll
    for (int kk = 0; kk < 4; ++kk) {
        if (kk < 3) {
#pragma unroll
            for (int m = 0; m < 2; ++m)
                af[(kk + 1) & 1][m] = *reinterpret_cast<const bf16x8*>(Ab + (size_t)m * 16 * ND + (kk + 1) * 32);
#pragma unroll
            for (int n = 0; n < 4; ++n)
                bfr[(kk + 1) & 1][n] = *reinterpret_cast<const bf16x8*>(Bb + (size_t)n * 16 * ND + (kk + 1) * 32);
        }
#pragma unroll
        for (int m = 0; m < 2; ++m)
#pragma unroll
            for (int n = 0; n < 4; ++n)
                acc[m][n] = __builtin_amdgcn_mfma_f32_16x16x32_bf16(af[kk & 1][m], bfr[kk & 1][n], acc[m][n], 0, 0, 0);
    }

    // Epilogue: i fixed per n; j varies over (m, r) -> lane-local partial sums.
#pragma unroll
    for (int n = 0; n < 4; ++n) {
        float s = 0.f;
#pragma unroll
        for (int m = 0; m < 2; ++m) {
#pragma unroll
            for (int r = 0; r < 4; ++r) {
                float sq = fmaf(-2.f, acc[m][n][r], skv[n] + imnv[m][r]);
                sq = fmaxf(sq, 0.f);
                float d;
                asm("v_sqrt_f32 %0, %1" : "=v"(d) : "v"(sq));
                float x = -1.442695041f * d;   // exp(-d) = 2^(-d*log2e)
                float e;
                asm("v_exp_f32 %0, %1" : "=v"(e) : "v"(x));
                s += e;
            }
        }
        s += __shfl_xor(s, 16);
        s += __shfl_xor(s, 32);
        if (lane < 16) lds_part[wr][wc * 64 + n * 16 + lane] = s;
    }
    __syncthreads();
    if (t < 128) {
        float v = (lds_part[0][t] + lds_part[1][t]) + (lds_part[2][t] + lds_part[3][t]);
        partial[(size_t)blockIdx.y * NB + tI + t] = v;
    }
}

// finalize: 32 blocks; per row sum 64 partials, v = log(rs)+diag; block-reduce;
// device atomicAdd + ticket, last block writes the mean.
__global__ void finalize_kernel(const float* __restrict__ partial,
                                const float* __restrict__ diag,
                                float* __restrict__ gacc, unsigned* __restrict__ ticket,
                                float* __restrict__ out) {
    const int i = blockIdx.x * 256 + threadIdx.x;
    float rs = 0.f;
#pragma unroll 8
    for (int c = 0; c < NJB; ++c) rs += partial[(size_t)c * NB + i];
    float v = __logf(rs) + diag[i];
    __shared__ float red[256];
    red[threadIdx.x] = v;
    __syncthreads();
    for (int st = 128; st > 0; st >>= 1) {
        if (threadIdx.x < st) red[threadIdx.x] += red[threadIdx.x + st];
        __syncthreads();
    }
    if (threadIdx.x == 0) {
        atomicAdd(gacc, red[0]);
        __threadfence();
        unsigned old = atomicAdd(ticket, 1u);
        if (old == (NB / 256) - 1) {
            float tot = atomicAdd(gacc, 0.f);   // device-coherent read
            out[0] = tot / (float)NB;
        }
    }
}

extern "C" void kernel_launch(void* const* d_in, const int* in_sizes, int n_in,
                              void* d_out, int out_size, void* d_ws, size_t ws_size,
                              hipStream_t stream) {
    const float* sk = (const float*)d_in[0];
    const float* im = (const float*)d_in[1];
    float* out = (float*)d_out;
    float* ws = (float*)d_ws;

    unsigned short* skb = (unsigned short*)ws;              // NB*ND bf16 (2 MB)
    unsigned short* imb = skb + (size_t)NB * ND;            // NB*ND bf16 (2 MB)
    float* fbase   = ws + (size_t)NB * ND;                  // 4 MB consumed above
    float* skn     = fbase;                                 // [NB]
    float* imn     = fbase + NB;                            // [NB]
    float* diag    = fbase + 2 * NB;                        // [NB]
    float* partial = fbase + 3 * NB;                        // [NJB][NB] (2 MB)
    float* gacc    = partial + (size_t)NJB * NB;            // [1]
    unsigned* ticket = (unsigned*)(gacc + 1);               // [1]

    prep_kernel<<<3 * NB * 16 / 256, 256, 0, stream>>>(
        sk, im, (ushort4*)skb, (ushort4*)imb, skn, imn, diag, gacc, ticket);
    dim3 grid(NB / 128, NB / 128);
    tile_kernel<<<grid, 512, 0, stream>>>(skb, imb, skn, imn, partial);
    finalize_kernel<<<NB / 256, 256, 0, stream>>>(partial, diag, gacc, ticket, out);
}

// Round 5
// 101.632 us; speedup vs baseline: 1.5370x; 1.5370x over previous
//
#include <hip/hip_runtime.h>
#include <math.h>

#define NB 8192
#define ND 128
#define NJB 64   // column-block partials per row

typedef __bf16 bf16x8 __attribute__((ext_vector_type(8)));
typedef float f32x4 __attribute__((ext_vector_type(4)));

typedef __attribute__((address_space(3))) void lds_void_t;
typedef __attribute__((address_space(1))) const void gconst_void_t;

__device__ __forceinline__ unsigned f2bf(float f) {
    union { float f; unsigned u; } v; v.f = f;
    unsigned r = v.u + 0x7FFFu + ((v.u >> 16) & 1u);  // RNE, inputs finite
    return r >> 16;
}

// prep: one wave per row. Reads each input row ONCE; emits bf16 copies,
// ||sk||^2, ||im||^2, diag = ||sk-im|| (fp32). Zeroes gacc/ticket.
__global__ void __launch_bounds__(256) prep_kernel(
    const float* __restrict__ sk, const float* __restrict__ im,
    unsigned* __restrict__ skb, unsigned* __restrict__ imb,
    float* __restrict__ skn, float* __restrict__ imn,
    float* __restrict__ diag, float* __restrict__ gacc,
    unsigned* __restrict__ ticket) {
    if (blockIdx.x == 0 && threadIdx.x == 0) { *gacc = 0.f; *ticket = 0u; }
    const int row = blockIdx.x * 4 + (threadIdx.x >> 6);
    const int l = threadIdx.x & 63;
    const size_t off = (size_t)row * ND + l * 2;
    const float2 a = *reinterpret_cast<const float2*>(sk + off);
    const float2 b = *reinterpret_cast<const float2*>(im + off);
    skb[row * 64 + l] = f2bf(a.x) | (f2bf(a.y) << 16);
    imb[row * 64 + l] = f2bf(b.x) | (f2bf(b.y) << 16);
    float sa = a.x * a.x + a.y * a.y;
    float sb = b.x * b.x + b.y * b.y;
    float dx = a.x - b.x, dy = a.y - b.y;
    float sd = dx * dx + dy * dy;
#pragma unroll
    for (int st = 1; st < 64; st <<= 1) {
        sa += __shfl_xor(sa, st);
        sb += __shfl_xor(sb, st);
        sd += __shfl_xor(sd, st);
    }
    if (l == 0) { skn[row] = sa; imn[row] = sb; diag[row] = sqrtf(sd); }
}

// tile: 128x128 per 256-thread block. A(im)/B(sk) tiles staged to LDS via
// global_load_lds (linear dest) with inverse-swizzled per-lane global source;
// ds_read uses matching XOR swizzle (slot ^= row&7) -> conflict-free.
// Swapped MFMA operands keep the j-sum lane-local; no atomics.
__global__ void __launch_bounds__(256) tile_kernel(
    const unsigned short* __restrict__ skb, const unsigned short* __restrict__ imb,
    const float* __restrict__ skn, const float* __restrict__ imn,
    float* __restrict__ partial) {
    __shared__ unsigned short Alds[128 * 128];   // im tile (j)
    __shared__ unsigned short Blds[128 * 128];   // sk tile (i)
    __shared__ float lds_part[2][128];

    const int t = threadIdx.x;
    const int w = t >> 6, lane = t & 63;
    const int tI = blockIdx.x * 128;   // sk (i) base
    const int tJ = blockIdx.y * 128;   // im (j) base

    // --- stage: wave w stages one 64-row half (16 KB) of A or B ---
    {
        const unsigned short* gsrc = (w < 2) ? imb : skb;
        const int half = w & 1;
        const int grow0 = ((w < 2) ? tJ : tI) + half * 64;
        unsigned short* ldst = ((w < 2) ? Alds : Blds) + half * 64 * ND;
#pragma unroll
        for (int q = 0; q < 16; ++q) {
            const int rl = q * 4 + (lane >> 4);          // local row in half
            const int cs = (lane & 15) ^ (rl & 7);       // inverse-swizzled slot
            const unsigned short* gp = gsrc + (size_t)(grow0 + rl) * ND + cs * 8;
            __builtin_amdgcn_global_load_lds((gconst_void_t*)gp,
                                             (lds_void_t*)(ldst + q * 4 * ND),
                                             16, 0, 0);
        }
    }

    const int wr = w >> 1, wc = w & 1;   // wr: j-half, wc: i-half
    const int hi = lane >> 4, lo = lane & 15;
    const int ibase = tI + wc * 64;
    const int jbase = tJ + wr * 64;

    // Hoist epilogue operands (hide under staging).
    float skv[4];
#pragma unroll
    for (int n = 0; n < 4; ++n) skv[n] = skn[ibase + n * 16 + lo];
    float imnv[4][4];
#pragma unroll
    for (int m = 0; m < 4; ++m) {
        float4 v = *reinterpret_cast<const float4*>(imn + jbase + m * 16 + hi * 4);
        imnv[m][0] = v.x; imnv[m][1] = v.y; imnv[m][2] = v.z; imnv[m][3] = v.w;
    }

    __syncthreads();   // drains vmcnt (global_load_lds) before LDS reads

    f32x4 acc[4][4];   // acc[m][n]: j = jbase+m*16+hi*4+r, i = ibase+n*16+lo
#pragma unroll
    for (int m = 0; m < 4; ++m)
#pragma unroll
        for (int n = 0; n < 4; ++n)
            acc[m][n] = (f32x4){0.f, 0.f, 0.f, 0.f};

    const char* Ab = (const char*)Alds;
    const char* Bb = (const char*)Blds;
    const int swz = (lo & 7) << 4;       // row&7 of every fragment row == lo&7
#pragma unroll
    for (int kk = 0; kk < 4; ++kk) {
        const int kb = (kk * 64 + hi * 16) ^ swz;   // swizzled byte col
        bf16x8 af[4], bfr[4];
#pragma unroll
        for (int m = 0; m < 4; ++m)
            af[m] = *reinterpret_cast<const bf16x8*>(Ab + (wr * 64 + m * 16 + lo) * 256 + kb);
#pragma unroll
        for (int n = 0; n < 4; ++n)
            bfr[n] = *reinterpret_cast<const bf16x8*>(Bb + (wc * 64 + n * 16 + lo) * 256 + kb);
#pragma unroll
        for (int m = 0; m < 4; ++m)
#pragma unroll
            for (int n = 0; n < 4; ++n)
                acc[m][n] = __builtin_amdgcn_mfma_f32_16x16x32_bf16(af[m], bfr[n], acc[m][n], 0, 0, 0);
    }

    // Epilogue: i fixed per n; j varies over (m, r) -> lane-local j-sums.
#pragma unroll
    for (int n = 0; n < 4; ++n) {
        float s = 0.f;
#pragma unroll
        for (int m = 0; m < 4; ++m) {
#pragma unroll
            for (int r = 0; r < 4; ++r) {
                float sq = fmaf(-2.f, acc[m][n][r], skv[n] + imnv[m][r]);
                sq = fmaxf(sq, 0.f);
                float d;
                asm("v_sqrt_f32 %0, %1" : "=v"(d) : "v"(sq));
                float x = -1.442695041f * d;   // exp(-d) = 2^(-d*log2e)
                float e;
                asm("v_exp_f32 %0, %1" : "=v"(e) : "v"(x));
                s += e;
            }
        }
        s += __shfl_xor(s, 16);
        s += __shfl_xor(s, 32);
        if (lane < 16) lds_part[wr][wc * 64 + n * 16 + lane] = s;
    }
    __syncthreads();
    if (t < 128)   // transposed: row-contiguous for finalize
        partial[(size_t)(tI + t) * NJB + blockIdx.y] =
            lds_part[0][t] + lds_part[1][t];
}

// finalize: thread per row; 16 contiguous float4 loads; log + diag; block
// reduce; device atomic + ticket, last block writes the mean.
__global__ void finalize_kernel(const float* __restrict__ partial,
                                const float* __restrict__ diag,
                                float* __restrict__ gacc, unsigned* __restrict__ ticket,
                                float* __restrict__ out) {
    const int i = blockIdx.x * 256 + threadIdx.x;
    const float4* p4 = reinterpret_cast<const float4*>(partial + (size_t)i * NJB);
    float rs = 0.f;
#pragma unroll
    for (int q = 0; q < NJB / 4; ++q) {
        float4 v = p4[q];
        rs += (v.x + v.y) + (v.z + v.w);
    }
    float v = __logf(rs) + diag[i];
    __shared__ float red[256];
    red[threadIdx.x] = v;
    __syncthreads();
    for (int st = 128; st > 0; st >>= 1) {
        if (threadIdx.x < st) red[threadIdx.x] += red[threadIdx.x + st];
        __syncthreads();
    }
    if (threadIdx.x == 0) {
        atomicAdd(gacc, red[0]);
        __threadfence();
        unsigned old = atomicAdd(ticket, 1u);
        if (old == (NB / 256) - 1) {
            float tot = atomicAdd(gacc, 0.f);   // device-coherent read
            out[0] = tot / (float)NB;
        }
    }
}

extern "C" void kernel_launch(void* const* d_in, const int* in_sizes, int n_in,
                              void* d_out, int out_size, void* d_ws, size_t ws_size,
                              hipStream_t stream) {
    const float* sk = (const float*)d_in[0];
    const float* im = (const float*)d_in[1];
    float* out = (float*)d_out;
    float* ws = (float*)d_ws;

    unsigned short* skb = (unsigned short*)ws;              // NB*ND bf16 (2 MB)
    unsigned short* imb = skb + (size_t)NB * ND;            // NB*ND bf16 (2 MB)
    float* fbase   = ws + (size_t)NB * ND;
    float* skn     = fbase;                                 // [NB]
    float* imn     = fbase + NB;                            // [NB]
    float* diag    = fbase + 2 * NB;                        // [NB]
    float* partial = fbase + 3 * NB;                        // [NB][NJB] (2 MB)
    float* gacc    = partial + (size_t)NB * NJB;            // [1]
    unsigned* ticket = (unsigned*)(gacc + 1);               // [1]

    prep_kernel<<<NB / 4, 256, 0, stream>>>(
        sk, im, (unsigned*)skb, (unsigned*)imb, skn, imn, diag, gacc, ticket);
    dim3 grid(NB / 128, NB / 128);
    tile_kernel<<<grid, 256, 0, stream>>>(skb, imb, skn, imn, partial);
    finalize_kernel<<<NB / 256, 256, 0, stream>>>(partial, diag, gacc, ticket, out);
}

// Round 6
// 98.045 us; speedup vs baseline: 1.5933x; 1.0366x over previous
//
#include <hip/hip_runtime.h>
#include <math.h>

#define NB 8192
#define ND 128
#define NJB 64   // column-block partials per row

// (log2 e)^2 — folded into the squared-norm terms so the epilogue needs no
// separate *log2e multiply: sqrt(c2*sq) = d*log2e, exp2(-that) = exp(-d).
#define C2F 2.0813689810056077f
#define NC2 (-4.1627379620112154f)   // -2*c2, fma coefficient on dot

typedef __bf16 bf16x8 __attribute__((ext_vector_type(8)));
typedef float f32x4 __attribute__((ext_vector_type(4)));

typedef __attribute__((address_space(3))) void lds_void_t;
typedef __attribute__((address_space(1))) const void gconst_void_t;

__device__ __forceinline__ unsigned f2bf(float f) {
    union { float f; unsigned u; } v; v.f = f;
    unsigned r = v.u + 0x7FFFu + ((v.u >> 16) & 1u);  // RNE, inputs finite
    return r >> 16;
}

// prep: 2 rows per wave (32 lanes each, float4 loads). Emits bf16 copies,
// c2-scaled ||sk||^2 / ||im||^2, diag = ||sk-im|| (fp32). Zeroes gacc/ticket.
__global__ void __launch_bounds__(256) prep_kernel(
    const float* __restrict__ sk, const float* __restrict__ im,
    unsigned short* __restrict__ skb, unsigned short* __restrict__ imb,
    float* __restrict__ skn, float* __restrict__ imn,
    float* __restrict__ diag, float* __restrict__ gacc,
    unsigned* __restrict__ ticket) {
    if (blockIdx.x == 0 && threadIdx.x == 0) { *gacc = 0.f; *ticket = 0u; }
    const int wave = threadIdx.x >> 6, lane = threadIdx.x & 63;
    const int half = lane >> 5, l32 = lane & 31;
    const int row = blockIdx.x * 8 + wave * 2 + half;
    const size_t off = (size_t)row * ND + l32 * 4;
    const float4 a = *reinterpret_cast<const float4*>(sk + off);
    const float4 b = *reinterpret_cast<const float4*>(im + off);
    ushort4 pa, pb;
    pa.x = (unsigned short)f2bf(a.x); pa.y = (unsigned short)f2bf(a.y);
    pa.z = (unsigned short)f2bf(a.z); pa.w = (unsigned short)f2bf(a.w);
    pb.x = (unsigned short)f2bf(b.x); pb.y = (unsigned short)f2bf(b.y);
    pb.z = (unsigned short)f2bf(b.z); pb.w = (unsigned short)f2bf(b.w);
    *reinterpret_cast<ushort4*>(skb + off) = pa;
    *reinterpret_cast<ushort4*>(imb + off) = pb;
    float sa = a.x * a.x + a.y * a.y + a.z * a.z + a.w * a.w;
    float sb = b.x * b.x + b.y * b.y + b.z * b.z + b.w * b.w;
    float dx = a.x - b.x, dy = a.y - b.y, dz = a.z - b.z, dw = a.w - b.w;
    float sd = dx * dx + dy * dy + dz * dz + dw * dw;
#pragma unroll
    for (int st = 1; st < 32; st <<= 1) {
        sa += __shfl_xor(sa, st);
        sb += __shfl_xor(sb, st);
        sd += __shfl_xor(sd, st);
    }
    if (l32 == 0) {
        skn[row] = sa * C2F;
        imn[row] = sb * C2F;
        diag[row] = sqrtf(sd);
    }
}

// tile: 128x128 per 512-thread block (8 waves, each 64j x 32i, acc[4][2]).
// Both bf16 tiles staged to LDS via global_load_lds (linear dest) with
// inverse-swizzled per-lane global source; ds_read applies the same
// involution (slot ^= row&15) -> spread across all 16 slots.
__global__ void __launch_bounds__(512, 4) tile_kernel(
    const unsigned short* __restrict__ skb, const unsigned short* __restrict__ imb,
    const float* __restrict__ skn, const float* __restrict__ imn,
    float* __restrict__ partial) {
    __shared__ unsigned short tiles[256 * 128];  // rows 0-127: im (A/j); 128-255: sk (B/i)
    __shared__ float lds_part[2][128];

    const int t = threadIdx.x;
    const int w = t >> 6, lane = t & 63;
    const int hi = lane >> 4, lo = lane & 15;
    const int tI = blockIdx.x * 128;   // sk (i) base
    const int tJ = blockIdx.y * 128;   // im (j) base

    // --- stage: wave w stages 32 rows of the concatenated [A;B] tile ---
    {
        const unsigned short* gsrc = (w < 4) ? imb : skb;
        const int grow0 = ((w < 4) ? tJ : tI) + (w & 3) * 32;
        unsigned short* ldst = tiles + (size_t)w * 32 * ND;
#pragma unroll
        for (int q = 0; q < 8; ++q) {
            const int rl = q * 4 + hi;                   // 0..31
            const int cs = lo ^ (rl & 15);               // inverse-swizzled slot
            const unsigned short* gp = gsrc + (size_t)(grow0 + rl) * ND + cs * 8;
            __builtin_amdgcn_global_load_lds((gconst_void_t*)gp,
                                             (lds_void_t*)(ldst + q * 4 * ND),
                                             16, 0, 0);
        }
    }

    const int wr = w >> 2, wc = w & 3;   // wr: j-half (64 rows), wc: i-quarter (32)
    const int ibase = tI + wc * 32;
    const int jbase = tJ + wr * 64;

    // Hoist epilogue operands (c2-scaled norms) — latency hides under staging.
    float skv2[2];
#pragma unroll
    for (int n = 0; n < 2; ++n) skv2[n] = skn[ibase + n * 16 + lo];
    float imnv2[4][4];
#pragma unroll
    for (int m = 0; m < 4; ++m) {
        float4 v = *reinterpret_cast<const float4*>(imn + jbase + m * 16 + hi * 4);
        imnv2[m][0] = v.x; imnv2[m][1] = v.y; imnv2[m][2] = v.z; imnv2[m][3] = v.w;
    }

    __syncthreads();   // compiler drains vmcnt before s_barrier -> tiles ready

    f32x4 acc[4][2];   // acc[m][n]: j = jbase+m*16+hi*4+r, i = ibase+n*16+lo
#pragma unroll
    for (int m = 0; m < 4; ++m)
#pragma unroll
        for (int n = 0; n < 2; ++n)
            acc[m][n] = (f32x4){0.f, 0.f, 0.f, 0.f};

    const char* Tb = (const char*)tiles;
#pragma unroll
    for (int kk = 0; kk < 4; ++kk) {
        const int cb = ((kk * 4 + hi) ^ lo) << 4;   // swizzled byte col
        bf16x8 af[4], bfr[2];
#pragma unroll
        for (int m = 0; m < 4; ++m)
            af[m] = *reinterpret_cast<const bf16x8*>(Tb + (wr * 64 + m * 16 + lo) * 256 + cb);
#pragma unroll
        for (int n = 0; n < 2; ++n)
            bfr[n] = *reinterpret_cast<const bf16x8*>(Tb + (128 + wc * 32 + n * 16 + lo) * 256 + cb);
#pragma unroll
        for (int m = 0; m < 4; ++m)
#pragma unroll
            for (int n = 0; n < 2; ++n)
                acc[m][n] = __builtin_amdgcn_mfma_f32_16x16x32_bf16(af[m], bfr[n], acc[m][n], 0, 0, 0);
    }

    // Epilogue: per lane, i fixed per n; j varies over (m, r).
    // sq2 = c2*(||sk||^2+||im||^2-2dot); d2 = sqrt(sq2) = d*log2e; e = 2^-d2.
#pragma unroll
    for (int n = 0; n < 2; ++n) {
        float s = 0.f;
#pragma unroll
        for (int m = 0; m < 4; ++m) {
#pragma unroll
            for (int r = 0; r < 4; ++r) {
                float sq2 = fmaf(NC2, acc[m][n][r], skv2[n]) + imnv2[m][r];
                sq2 = fmaxf(sq2, 0.f);
                float d2;
                asm("v_sqrt_f32 %0, %1" : "=v"(d2) : "v"(sq2));
                float e;
                asm("v_exp_f32 %0, -%1" : "=v"(e) : "v"(d2));
                s += e;
            }
        }
        s += __shfl_xor(s, 16);
        s += __shfl_xor(s, 32);
        if (lane < 16) lds_part[wr][wc * 32 + n * 16 + lane] = s;
    }
    __syncthreads();
    if (t < 128)   // transposed: row-contiguous for finalize
        partial[(size_t)(tI + t) * NJB + blockIdx.y] =
            lds_part[0][t] + lds_part[1][t];
}

// finalize: thread per row; 16 contiguous float4 loads; log + diag; block
// reduce; device atomic + ticket, last block writes the mean.
__global__ void finalize_kernel(const float* __restrict__ partial,
                                const float* __restrict__ diag,
                                float* __restrict__ gacc, unsigned* __restrict__ ticket,
                                float* __restrict__ out) {
    const int i = blockIdx.x * 256 + threadIdx.x;
    const float4* p4 = reinterpret_cast<const float4*>(partial + (size_t)i * NJB);
    float rs = 0.f;
#pragma unroll
    for (int q = 0; q < NJB / 4; ++q) {
        float4 v = p4[q];
        rs += (v.x + v.y) + (v.z + v.w);
    }
    float v = __logf(rs) + diag[i];
    __shared__ float red[256];
    red[threadIdx.x] = v;
    __syncthreads();
    for (int st = 128; st > 0; st >>= 1) {
        if (threadIdx.x < st) red[threadIdx.x] += red[threadIdx.x + st];
        __syncthreads();
    }
    if (threadIdx.x == 0) {
        atomicAdd(gacc, red[0]);
        __threadfence();
        unsigned old = atomicAdd(ticket, 1u);
        if (old == (NB / 256) - 1) {
            float tot = atomicAdd(gacc, 0.f);   // device-coherent read
            out[0] = tot / (float)NB;
        }
    }
}

extern "C" void kernel_launch(void* const* d_in, const int* in_sizes, int n_in,
                              void* d_out, int out_size, void* d_ws, size_t ws_size,
                              hipStream_t stream) {
    const float* sk = (const float*)d_in[0];
    const float* im = (const float*)d_in[1];
    float* out = (float*)d_out;
    float* ws = (float*)d_ws;

    unsigned short* skb = (unsigned short*)ws;              // NB*ND bf16 (2 MB)
    unsigned short* imb = skb + (size_t)NB * ND;            // NB*ND bf16 (2 MB)
    float* fbase   = ws + (size_t)NB * ND;
    float* skn     = fbase;                                 // [NB] (c2-scaled)
    float* imn     = fbase + NB;                            // [NB] (c2-scaled)
    float* diag    = fbase + 2 * NB;                        // [NB]
    float* partial = fbase + 3 * NB;                        // [NB][NJB] (2 MB)
    float* gacc    = partial + (size_t)NB * NJB;            // [1]
    unsigned* ticket = (unsigned*)(gacc + 1);               // [1]

    prep_kernel<<<NB / 8, 256, 0, stream>>>(
        sk, im, skb, imb, skn, imn, diag, gacc, ticket);
    dim3 grid(NB / 128, NB / 128);
    tile_kernel<<<grid, 512, 0, stream>>>(skb, imb, skn, imn, partial);
    finalize_kernel<<<NB / 256, 256, 0, stream>>>(partial, diag, gacc, ticket, out);
}